// Round 8
// baseline (211.200 us; speedup 1.0000x reference)
//
#include <hip/hip_runtime.h>
#include <hip/hip_cooperative_groups.h>

namespace cg = cooperative_groups;

#define NN 2048     // nodes per graph
#define NG 64       // graphs
#define NE 16384    // edges per graph
#define BB 65536    // batch
#define META 64
#define TXD 8
#define NOISE 128

// ws layout (32-bit words from base):
//   graph_out [64][128]     @ 0        (8192)   zeroed in stage A
//   deg4      [64][4][2048] @ 8192     (524288) int partials (write-once)
//   acc4      [64][4][2048] @ 532480   (524288) float partials (write-once)

// ---------------------------------------------------------------------------
// Cooperative GCN pipeline: 256 blocks (4 per graph), ONE launch, two
// grid.sync()s (harness-sanctioned replacement for R7's flag spin, which
// hung). Stage A: deg partial (own dst quarter, LDS int atomics) -> sync ->
// Stage B: full dinv from 4 partials; acc partial (native ds_add_f32) ->
// sync -> Stage C: emb slice from 4 acc partials; fold with 8-deep ILP;
// native global f32 atomic into graph_out (zeroed in stage A).
// Edge fetch now chip-parallel: R6 showed 64-block version was latency-bound
// at 187 GB/s / 1.5% VALUBusy.
// ---------------------------------------------------------------------------
__global__ __launch_bounds__(256) void gcn_coop_kernel(
    const int* __restrict__ edges,     // [64,2,16384]
    const float* __restrict__ gcn_w,
    const float* __restrict__ gcn_b,
    const float* __restrict__ emb_W,   // [2089,128]
    float* __restrict__ graph_out,     // [64][128]
    int*   __restrict__ deg4,          // [64][4][2048]
    float* __restrict__ acc4)          // [64][4][2048]
{
    __shared__ int   s_cnt[NN];        // 8 KB; reused as float s_val in stage B
    __shared__ float s_dinv[NN];       // 8 KB
    __shared__ float s_emb[512];       // 2 KB
    __shared__ float s_part[NOISE];    // 0.5 KB

    const int b = blockIdx.x, g = b >> 2, q = b & 3, tid = threadIdx.x;
    cg::grid_group grid = cg::this_grid();

    // zero graph_out for stage C's atomics (2 grid syncs before use)
    if (q == 0 && tid < NOISE) graph_out[g * NOISE + tid] = 0.0f;

    // prefetch own dst quarter: 4 int4 = 16 VGPRs (kept live through stage B)
    const int4* __restrict__ ed =
        (const int4*)(edges + (size_t)g * 2 * NE + NE + q * 4096);
    int4 ds[4];
    #pragma unroll
    for (int k = 0; k < 4; ++k) ds[k] = ed[k * 256 + tid];

    // ---- stage A: degree partial for this quarter ----
    for (int n = tid; n < NN; n += 256) s_cnt[n] = 0;
    __syncthreads();
    #pragma unroll
    for (int k = 0; k < 4; ++k) {
        atomicAdd(&s_cnt[ds[k].x], 1);
        atomicAdd(&s_cnt[ds[k].y], 1);
        atomicAdd(&s_cnt[ds[k].z], 1);
        atomicAdd(&s_cnt[ds[k].w], 1);
    }
    __syncthreads();
    {
        int* dp = deg4 + ((size_t)g * 4 + q) * NN;
        for (int n = tid; n < NN; n += 256) dp[n] = s_cnt[n];
    }
    grid.sync();

    // ---- stage B: full dinv (redundant per block); acc partial ----
    {
        const int* d0 = deg4 + (size_t)g * 4 * NN;
        for (int n = tid; n < NN; n += 256) {
            int d = d0[n] + d0[NN + n] + d0[2 * NN + n] + d0[3 * NN + n] + 1;
            s_dinv[n] = rsqrtf((float)d);
        }
    }
    float* s_val = (float*)s_cnt;      // union: s_cnt dead after stage A
    for (int n = tid; n < NN; n += 256) s_val[n] = 0.0f;
    __syncthreads();
    {
        const int4* __restrict__ es =
            (const int4*)(edges + (size_t)g * 2 * NE + q * 4096);
        #pragma unroll
        for (int k = 0; k < 4; ++k) {
            int4 sr = es[k * 256 + tid];
            unsafeAtomicAdd(&s_val[ds[k].x], s_dinv[sr.x]);
            unsafeAtomicAdd(&s_val[ds[k].y], s_dinv[sr.y]);
            unsafeAtomicAdd(&s_val[ds[k].z], s_dinv[sr.z]);
            unsafeAtomicAdd(&s_val[ds[k].w], s_dinv[sr.w]);
        }
    }
    __syncthreads();
    {
        float* ap = acc4 + ((size_t)g * 4 + q) * NN;
        for (int n = tid; n < NN; n += 256) ap[n] = s_val[n];
    }
    grid.sync();

    // ---- stage C: emb for own 512-node slice; fold; atomic accumulate ----
    {
        const float* a0 = acc4 + (size_t)g * 4 * NN + q * 512;
        const float w = gcn_w[0], bb = gcn_b[0];
        for (int n = tid; n < 512; n += 256) {
            float sum = a0[n] + a0[NN + n] + a0[2 * NN + n] + a0[3 * NN + n];
            float di = s_dinv[q * 512 + n];
            s_emb[n] = di * (sum + di) * w + bb;
        }
    }
    __syncthreads();
    {
        const int c = tid & 127, h = tid >> 7;
        const float* __restrict__ Wp =
            emb_W + (size_t)(q * 512 + h * 256) * NOISE + c;
        const float* __restrict__ ep = s_emb + h * 256;
        float a0 = 0.f, a1 = 0.f, a2 = 0.f, a3 = 0.f;
        float a4 = 0.f, a5 = 0.f, a6 = 0.f, a7 = 0.f;
        #pragma unroll 2
        for (int i = 0; i < 256; i += 8) {
            a0 = fmaf(ep[i + 0], Wp[(i + 0) * NOISE], a0);
            a1 = fmaf(ep[i + 1], Wp[(i + 1) * NOISE], a1);
            a2 = fmaf(ep[i + 2], Wp[(i + 2) * NOISE], a2);
            a3 = fmaf(ep[i + 3], Wp[(i + 3) * NOISE], a3);
            a4 = fmaf(ep[i + 4], Wp[(i + 4) * NOISE], a4);
            a5 = fmaf(ep[i + 5], Wp[(i + 5) * NOISE], a5);
            a6 = fmaf(ep[i + 6], Wp[(i + 6) * NOISE], a6);
            a7 = fmaf(ep[i + 7], Wp[(i + 7) * NOISE], a7);
        }
        float acc_ = ((a0 + a1) + (a2 + a3)) + ((a4 + a5) + (a6 + a7));
        if (h == 1) s_part[c] = acc_;
        __syncthreads();
        if (h == 0) unsafeAtomicAdd(&graph_out[g * NOISE + c], acc_ + s_part[c]);
    }
}

// ---------------------------------------------------------------------------
// Kernel C: main batched kernel (round-0 proven version, untouched).
// ---------------------------------------------------------------------------
#define ROWS 32
__global__ __launch_bounds__(256, 3) void main_kernel(
    const int* __restrict__ bg,          // [B]
    const float* __restrict__ chain,     // [B]
    const float* __restrict__ trig_in,   // [B,64]
    const float* __restrict__ txs,       // [B,8]
    const float* __restrict__ trig_W,    // [64,32]
    const float* __restrict__ trig_b,    // [32]
    const float* __restrict__ emb_W,     // [2089,128]
    const float* __restrict__ emb_b,     // [128]
    const float* __restrict__ graph_out, // [64,128]
    float* __restrict__ out)             // [B,128]
{
    __shared__ float s_td[ROWS * 68];    // trigger rows, stride 68 (8.7 KB)
    __shared__ float s_twT[32 * 68];     // trig_W^T [j][i], stride 68 (8.7 KB)
    __shared__ float s_trig[ROWS * 36];  // relu'd trig, stride 36 (4.6 KB)
    __shared__ float s_tx[ROWS * TXD];   // 1 KB
    __shared__ float s_ch[ROWS];
    __shared__ int   s_gi[ROWS];

    const int tid = threadIdx.x;
    const int row0 = blockIdx.x * ROWS;

    // --- stage trigger rows: 32x64 floats = 512 float4 ---
    {
        const float4* __restrict__ gsrc =
            (const float4*)(trig_in + (size_t)row0 * META);
        #pragma unroll
        for (int k = 0; k < 2; ++k) {
            int t = tid + k * 256;
            int r = t >> 4, i4 = t & 15;
            *(float4*)&s_td[r * 68 + i4 * 4] = gsrc[t];
        }
    }
    // --- stage trig_W transposed: 512 float4, scatter ---
    {
        const float4* __restrict__ gsrc = (const float4*)trig_W;
        #pragma unroll
        for (int k = 0; k < 2; ++k) {
            int t = tid + k * 256;
            int i = t >> 3, j4 = (t & 7) * 4;
            float4 v = gsrc[t];
            s_twT[(j4 + 0) * 68 + i] = v.x;
            s_twT[(j4 + 1) * 68 + i] = v.y;
            s_twT[(j4 + 2) * 68 + i] = v.z;
            s_twT[(j4 + 3) * 68 + i] = v.w;
        }
    }
    // --- stage row metadata: tx (64 float4), chain, graph idx ---
    if (tid < 64) {
        int r = tid >> 1, k4 = (tid & 1) * 4;
        *(float4*)&s_tx[r * TXD + k4] =
            ((const float4*)(txs + (size_t)row0 * TXD))[tid];
    } else if (tid < 96) {
        int r = tid - 64;
        s_ch[r] = chain[row0 + r];
    } else if (tid < 128) {
        int r = tid - 96;
        s_gi[r] = bg[row0 + r];
    }

    // --- per-thread column-pair weights (overlap with staging latency) ---
    const int n0 = (tid & 63) * 2;
    float2 w2[32], w3[TXD];
    #pragma unroll
    for (int j = 0; j < 32; ++j)
        w2[j] = *(const float2*)&emb_W[(size_t)(2049 + j) * NOISE + n0];
    #pragma unroll
    for (int k = 0; k < TXD; ++k)
        w3[k] = *(const float2*)&emb_W[(size_t)(2081 + k) * NOISE + n0];
    const float2 w1   = *(const float2*)&emb_W[(size_t)2048 * NOISE + n0];
    const float2 bias = *(const float2*)&emb_b[n0];

    __syncthreads();

    // --- phase 1: trig = relu(td @ trig_W + b); cols {j0, j0+16} x 2 rows ---
    {
        const int j0 = tid & 15;            // bank-spread: 68*j0 covers all quads
        const int r0 = (tid >> 4) * 2;
        const float* __restrict__ tw0 = s_twT + j0 * 68;
        const float* __restrict__ tw1 = s_twT + (j0 + 16) * 68;
        const float* __restrict__ td0 = s_td + r0 * 68;
        const float* __restrict__ td1 = s_td + (r0 + 1) * 68;
        float b0 = trig_b[j0], b1 = trig_b[j0 + 16];
        float a00 = b0, a01 = b1, a10 = b0, a11 = b1;
        #pragma unroll
        for (int i = 0; i < META; i += 4) {
            float4 u0 = *(const float4*)(tw0 + i);
            float4 u1 = *(const float4*)(tw1 + i);
            float4 t0 = *(const float4*)(td0 + i);
            float4 t1 = *(const float4*)(td1 + i);
            a00 = fmaf(t0.x, u0.x, a00); a00 = fmaf(t0.y, u0.y, a00);
            a00 = fmaf(t0.z, u0.z, a00); a00 = fmaf(t0.w, u0.w, a00);
            a01 = fmaf(t0.x, u1.x, a01); a01 = fmaf(t0.y, u1.y, a01);
            a01 = fmaf(t0.z, u1.z, a01); a01 = fmaf(t0.w, u1.w, a01);
            a10 = fmaf(t1.x, u0.x, a10); a10 = fmaf(t1.y, u0.y, a10);
            a10 = fmaf(t1.z, u0.z, a10); a10 = fmaf(t1.w, u0.w, a10);
            a11 = fmaf(t1.x, u1.x, a11); a11 = fmaf(t1.y, u1.y, a11);
            a11 = fmaf(t1.z, u1.z, a11); a11 = fmaf(t1.w, u1.w, a11);
        }
        s_trig[r0 * 36 + j0]            = fmaxf(a00, 0.f);
        s_trig[r0 * 36 + j0 + 16]       = fmaxf(a01, 0.f);
        s_trig[(r0 + 1) * 36 + j0]      = fmaxf(a10, 0.f);
        s_trig[(r0 + 1) * 36 + j0 + 16] = fmaxf(a11, 0.f);
    }
    __syncthreads();

    // --- phase 2: 8 rows x 2 cols per thread ---
    const int wv = tid >> 6;   // rows wave-uniform -> LDS broadcasts
    // batch the graph_out gathers (independent -> one latency exposure)
    int   gs[8];
    float chs[8];
    #pragma unroll
    for (int p = 0; p < 8; ++p) {
        const int r = p * 4 + wv;
        gs[p]  = s_gi[r];
        chs[p] = s_ch[r];
    }
    float2 go[8];
    #pragma unroll
    for (int p = 0; p < 8; ++p)
        go[p] = *(const float2*)&graph_out[gs[p] * NOISE + n0];

    #pragma unroll
    for (int p = 0; p < 8; ++p) {
        const int r = p * 4 + wv;
        const int row = row0 + r;
        float ax = bias.x + go[p].x + chs[p] * w1.x;
        float ay = bias.y + go[p].y + chs[p] * w1.y;
        const float4* __restrict__ tx4 = (const float4*)(s_tx + r * TXD);
        float4 t0 = tx4[0], t1 = tx4[1];
        ax = fmaf(t0.x, w3[0].x, ax); ay = fmaf(t0.x, w3[0].y, ay);
        ax = fmaf(t0.y, w3[1].x, ax); ay = fmaf(t0.y, w3[1].y, ay);
        ax = fmaf(t0.z, w3[2].x, ax); ay = fmaf(t0.z, w3[2].y, ay);
        ax = fmaf(t0.w, w3[3].x, ax); ay = fmaf(t0.w, w3[3].y, ay);
        ax = fmaf(t1.x, w3[4].x, ax); ay = fmaf(t1.x, w3[4].y, ay);
        ax = fmaf(t1.y, w3[5].x, ax); ay = fmaf(t1.y, w3[5].y, ay);
        ax = fmaf(t1.z, w3[6].x, ax); ay = fmaf(t1.z, w3[6].y, ay);
        ax = fmaf(t1.w, w3[7].x, ax); ay = fmaf(t1.w, w3[7].y, ay);
        const float* __restrict__ tg = s_trig + r * 36;
        #pragma unroll
        for (int q = 0; q < 8; ++q) {
            float4 t4 = *(const float4*)(tg + q * 4);   // broadcast b128
            ax = fmaf(t4.x, w2[4 * q + 0].x, ax); ay = fmaf(t4.x, w2[4 * q + 0].y, ay);
            ax = fmaf(t4.y, w2[4 * q + 1].x, ax); ay = fmaf(t4.y, w2[4 * q + 1].y, ay);
            ax = fmaf(t4.z, w2[4 * q + 2].x, ax); ay = fmaf(t4.z, w2[4 * q + 2].y, ay);
            ax = fmaf(t4.w, w2[4 * q + 3].x, ax); ay = fmaf(t4.w, w2[4 * q + 3].y, ay);
        }
        *(float2*)&out[(size_t)row * NOISE + n0] = make_float2(ax, ay);
    }
}

extern "C" void kernel_launch(void* const* d_in, const int* in_sizes, int n_in,
                              void* d_out, int out_size, void* d_ws, size_t ws_size,
                              hipStream_t stream) {
    const int*   bg      = (const int*)d_in[0];
    const float* chain   = (const float*)d_in[1];
    const float* trig_in = (const float*)d_in[2];
    const float* txs     = (const float*)d_in[3];
    const int*   edges   = (const int*)d_in[4];
    const float* gcn_w   = (const float*)d_in[5];
    const float* gcn_b   = (const float*)d_in[6];
    const float* trig_W  = (const float*)d_in[7];
    const float* trig_b  = (const float*)d_in[8];
    const float* emb_W   = (const float*)d_in[9];
    const float* emb_b   = (const float*)d_in[10];
    float* out = (float*)d_out;

    float* wsf       = (float*)d_ws;
    float* graph_out = wsf;                      // [64][128]
    int*   deg4      = (int*)(wsf + 8192);       // [64][4][2048]
    float* acc4      = wsf + 8192 + 524288;      // [64][4][2048]

    void* kargs[] = {
        (void*)&edges, (void*)&gcn_w, (void*)&gcn_b, (void*)&emb_W,
        (void*)&graph_out, (void*)&deg4, (void*)&acc4
    };
    hipLaunchCooperativeKernel(reinterpret_cast<void*>(gcn_coop_kernel),
                               dim3(NG * 4), dim3(256), kargs, 0, stream);
    main_kernel<<<BB / ROWS, 256, 0, stream>>>(bg, chain, trig_in, txs, trig_W,
                                               trig_b, emb_W, emb_b, graph_out, out);
}

// Round 9
// 134.489 us; speedup vs baseline: 1.5704x; 1.5704x over previous
//
#include <hip/hip_runtime.h>

#define NN 2048     // nodes per graph
#define NG 64       // graphs
#define NE 16384    // edges per graph
#define BB 65536    // batch
#define META 64
#define TXD 8
#define NOISE 128

// ws layout (32-bit words from base):
//   graph_out [64][128]     @ 0        (8192)   zeroed by deg_kernel
//   deg4      [64][4][2048] @ 8192     (524288) int partials (write-once)
//   acc4      [64][4][2048] @ 532480   (524288) float partials (write-once)
// No cross-block sync: partials are plain-stored, readers run in later
// launches. Idempotent across graph replays; no zero-init needed (except
// graph_out, zeroed 2 launches before its atomics).

// ---------------------------------------------------------------------------
// Kernel 1: degree partials. 256 blocks = 4 per graph, own dst quarter.
// ---------------------------------------------------------------------------
__global__ __launch_bounds__(256) void deg_kernel(
    const int* __restrict__ edges,     // [64,2,16384]
    int*   __restrict__ deg4,          // [64][4][2048]
    float* __restrict__ graph_out)     // [64][128] (zeroed here)
{
    __shared__ int s_cnt[NN];          // 8 KB
    const int b = blockIdx.x, g = b >> 2, q = b & 3, tid = threadIdx.x;

    if (q == 0 && tid < NOISE) graph_out[g * NOISE + tid] = 0.0f;

    const int4* __restrict__ ed =
        (const int4*)(edges + (size_t)g * 2 * NE + NE + q * 4096);
    int4 ds[4];
    #pragma unroll
    for (int k = 0; k < 4; ++k) ds[k] = ed[k * 256 + tid];

    for (int n = tid; n < NN; n += 256) s_cnt[n] = 0;
    __syncthreads();
    #pragma unroll
    for (int k = 0; k < 4; ++k) {
        atomicAdd(&s_cnt[ds[k].x], 1);
        atomicAdd(&s_cnt[ds[k].y], 1);
        atomicAdd(&s_cnt[ds[k].z], 1);
        atomicAdd(&s_cnt[ds[k].w], 1);
    }
    __syncthreads();
    int* dp = deg4 + ((size_t)g * 4 + q) * NN;
    for (int n = tid; n < NN; n += 256) dp[n] = s_cnt[n];
}

// ---------------------------------------------------------------------------
// Kernel 2: aggregation partials. 256 blocks = 4 per graph.
// dinv from summed deg partials; s_val[dst] += dinv[src] via NATIVE
// ds_add_f32 (unsafeAtomicAdd — plain float atomicAdd is a CAS loop here);
// dst factor deferred to fold. Plain-store partial.
// ---------------------------------------------------------------------------
__global__ __launch_bounds__(256) void acc_kernel(
    const int* __restrict__ edges,     // [64,2,16384]
    const int* __restrict__ deg4,      // [64][4][2048]
    float* __restrict__ acc4)          // [64][4][2048]
{
    __shared__ float s_dinv[NN];       // 8 KB
    __shared__ float s_val[NN];        // 8 KB
    const int b = blockIdx.x, g = b >> 2, q = b & 3, tid = threadIdx.x;

    // prefetch own edge quarter: 8 int4 = 32 VGPRs in flight
    const int4* __restrict__ es =
        (const int4*)(edges + (size_t)g * 2 * NE + q * 4096);
    const int4* __restrict__ ed =
        (const int4*)(edges + (size_t)g * 2 * NE + NE + q * 4096);
    int4 ds[4], sr[4];
    #pragma unroll
    for (int k = 0; k < 4; ++k) ds[k] = ed[k * 256 + tid];
    #pragma unroll
    for (int k = 0; k < 4; ++k) sr[k] = es[k * 256 + tid];

    {
        const int* d0 = deg4 + (size_t)g * 4 * NN;
        for (int n = tid; n < NN; n += 256) {
            int d = d0[n] + d0[NN + n] + d0[2 * NN + n] + d0[3 * NN + n] + 1;
            s_dinv[n] = rsqrtf((float)d);
            s_val[n] = 0.0f;
        }
    }
    __syncthreads();
    #pragma unroll
    for (int k = 0; k < 4; ++k) {
        unsafeAtomicAdd(&s_val[ds[k].x], s_dinv[sr[k].x]);
        unsafeAtomicAdd(&s_val[ds[k].y], s_dinv[sr[k].y]);
        unsafeAtomicAdd(&s_val[ds[k].z], s_dinv[sr[k].z]);
        unsafeAtomicAdd(&s_val[ds[k].w], s_dinv[sr[k].w]);
    }
    __syncthreads();
    float* ap = acc4 + ((size_t)g * 4 + q) * NN;
    for (int n = tid; n < NN; n += 256) ap[n] = s_val[n];
}

// ---------------------------------------------------------------------------
// Kernel 3: fold. 1024 blocks = 64 graphs x 16 chunks of 128 nodes.
// emb computed on the fly from deg/acc partials: di*(sum + di)*w + b.
// GEMM chunk then native global_atomic_add_f32 into graph_out.
// ---------------------------------------------------------------------------
__global__ __launch_bounds__(256) void fold_kernel(
    const int* __restrict__ deg4,      // [64][4][2048]
    const float* __restrict__ acc4,    // [64][4][2048]
    const float* __restrict__ gcn_w,
    const float* __restrict__ gcn_b,
    const float* __restrict__ emb_W,   // [2089,128]
    float* __restrict__ graph_out)     // [64][128], zeroed by deg_kernel
{
    __shared__ float s_e[128];
    __shared__ float s_red[128];
    const int tid = threadIdx.x;
    const int g = blockIdx.x >> 4, chunk = blockIdx.x & 15;
    const int n0 = chunk * 128;
    if (tid < 128) {
        const int n = n0 + tid;
        const int* d0 = deg4 + (size_t)g * 4 * NN + n;
        int d = d0[0] + d0[NN] + d0[2 * NN] + d0[3 * NN] + 1;
        float di = rsqrtf((float)d);
        const float* a0 = acc4 + (size_t)g * 4 * NN + n;
        float sum = a0[0] + a0[NN] + a0[2 * NN] + a0[3 * NN];
        s_e[tid] = di * (sum + di) * gcn_w[0] + gcn_b[0];
    }
    __syncthreads();
    const int c = tid & 127, h = tid >> 7;
    const float* __restrict__ Wp = emb_W + (size_t)(n0 + h * 64) * NOISE + c;
    const float* __restrict__ ep = s_e + h * 64;
    float a0 = 0.f, a1 = 0.f, a2 = 0.f, a3 = 0.f;
    #pragma unroll
    for (int i = 0; i < 64; i += 4) {
        a0 = fmaf(ep[i + 0], Wp[(i + 0) * NOISE], a0);
        a1 = fmaf(ep[i + 1], Wp[(i + 1) * NOISE], a1);
        a2 = fmaf(ep[i + 2], Wp[(i + 2) * NOISE], a2);
        a3 = fmaf(ep[i + 3], Wp[(i + 3) * NOISE], a3);
    }
    float acc = (a0 + a1) + (a2 + a3);
    if (h == 1) s_red[c] = acc;
    __syncthreads();
    if (h == 0) unsafeAtomicAdd(&graph_out[g * NOISE + c], acc + s_red[c]);
}

// ---------------------------------------------------------------------------
// Kernel C: main batched kernel (round-0 proven version, untouched).
// ---------------------------------------------------------------------------
#define ROWS 32
__global__ __launch_bounds__(256, 3) void main_kernel(
    const int* __restrict__ bg,          // [B]
    const float* __restrict__ chain,     // [B]
    const float* __restrict__ trig_in,   // [B,64]
    const float* __restrict__ txs,       // [B,8]
    const float* __restrict__ trig_W,    // [64,32]
    const float* __restrict__ trig_b,    // [32]
    const float* __restrict__ emb_W,     // [2089,128]
    const float* __restrict__ emb_b,     // [128]
    const float* __restrict__ graph_out, // [64,128]
    float* __restrict__ out)             // [B,128]
{
    __shared__ float s_td[ROWS * 68];    // trigger rows, stride 68 (8.7 KB)
    __shared__ float s_twT[32 * 68];     // trig_W^T [j][i], stride 68 (8.7 KB)
    __shared__ float s_trig[ROWS * 36];  // relu'd trig, stride 36 (4.6 KB)
    __shared__ float s_tx[ROWS * TXD];   // 1 KB
    __shared__ float s_ch[ROWS];
    __shared__ int   s_gi[ROWS];

    const int tid = threadIdx.x;
    const int row0 = blockIdx.x * ROWS;

    // --- stage trigger rows: 32x64 floats = 512 float4 ---
    {
        const float4* __restrict__ gsrc =
            (const float4*)(trig_in + (size_t)row0 * META);
        #pragma unroll
        for (int k = 0; k < 2; ++k) {
            int t = tid + k * 256;
            int r = t >> 4, i4 = t & 15;
            *(float4*)&s_td[r * 68 + i4 * 4] = gsrc[t];
        }
    }
    // --- stage trig_W transposed: 512 float4, scatter ---
    {
        const float4* __restrict__ gsrc = (const float4*)trig_W;
        #pragma unroll
        for (int k = 0; k < 2; ++k) {
            int t = tid + k * 256;
            int i = t >> 3, j4 = (t & 7) * 4;
            float4 v = gsrc[t];
            s_twT[(j4 + 0) * 68 + i] = v.x;
            s_twT[(j4 + 1) * 68 + i] = v.y;
            s_twT[(j4 + 2) * 68 + i] = v.z;
            s_twT[(j4 + 3) * 68 + i] = v.w;
        }
    }
    // --- stage row metadata: tx (64 float4), chain, graph idx ---
    if (tid < 64) {
        int r = tid >> 1, k4 = (tid & 1) * 4;
        *(float4*)&s_tx[r * TXD + k4] =
            ((const float4*)(txs + (size_t)row0 * TXD))[tid];
    } else if (tid < 96) {
        int r = tid - 64;
        s_ch[r] = chain[row0 + r];
    } else if (tid < 128) {
        int r = tid - 96;
        s_gi[r] = bg[row0 + r];
    }

    // --- per-thread column-pair weights (overlap with staging latency) ---
    const int n0 = (tid & 63) * 2;
    float2 w2[32], w3[TXD];
    #pragma unroll
    for (int j = 0; j < 32; ++j)
        w2[j] = *(const float2*)&emb_W[(size_t)(2049 + j) * NOISE + n0];
    #pragma unroll
    for (int k = 0; k < TXD; ++k)
        w3[k] = *(const float2*)&emb_W[(size_t)(2081 + k) * NOISE + n0];
    const float2 w1   = *(const float2*)&emb_W[(size_t)2048 * NOISE + n0];
    const float2 bias = *(const float2*)&emb_b[n0];

    __syncthreads();

    // --- phase 1: trig = relu(td @ trig_W + b); cols {j0, j0+16} x 2 rows ---
    {
        const int j0 = tid & 15;            // bank-spread: 68*j0 covers all quads
        const int r0 = (tid >> 4) * 2;
        const float* __restrict__ tw0 = s_twT + j0 * 68;
        const float* __restrict__ tw1 = s_twT + (j0 + 16) * 68;
        const float* __restrict__ td0 = s_td + r0 * 68;
        const float* __restrict__ td1 = s_td + (r0 + 1) * 68;
        float b0 = trig_b[j0], b1 = trig_b[j0 + 16];
        float a00 = b0, a01 = b1, a10 = b0, a11 = b1;
        #pragma unroll
        for (int i = 0; i < META; i += 4) {
            float4 u0 = *(const float4*)(tw0 + i);
            float4 u1 = *(const float4*)(tw1 + i);
            float4 t0 = *(const float4*)(td0 + i);
            float4 t1 = *(const float4*)(td1 + i);
            a00 = fmaf(t0.x, u0.x, a00); a00 = fmaf(t0.y, u0.y, a00);
            a00 = fmaf(t0.z, u0.z, a00); a00 = fmaf(t0.w, u0.w, a00);
            a01 = fmaf(t0.x, u1.x, a01); a01 = fmaf(t0.y, u1.y, a01);
            a01 = fmaf(t0.z, u1.z, a01); a01 = fmaf(t0.w, u1.w, a01);
            a10 = fmaf(t1.x, u0.x, a10); a10 = fmaf(t1.y, u0.y, a10);
            a10 = fmaf(t1.z, u0.z, a10); a10 = fmaf(t1.w, u0.w, a10);
            a11 = fmaf(t1.x, u1.x, a11); a11 = fmaf(t1.y, u1.y, a11);
            a11 = fmaf(t1.z, u1.z, a11); a11 = fmaf(t1.w, u1.w, a11);
        }
        s_trig[r0 * 36 + j0]            = fmaxf(a00, 0.f);
        s_trig[r0 * 36 + j0 + 16]       = fmaxf(a01, 0.f);
        s_trig[(r0 + 1) * 36 + j0]      = fmaxf(a10, 0.f);
        s_trig[(r0 + 1) * 36 + j0 + 16] = fmaxf(a11, 0.f);
    }
    __syncthreads();

    // --- phase 2: 8 rows x 2 cols per thread ---
    const int wv = tid >> 6;   // rows wave-uniform -> LDS broadcasts
    // batch the graph_out gathers (independent -> one latency exposure)
    int   gs[8];
    float chs[8];
    #pragma unroll
    for (int p = 0; p < 8; ++p) {
        const int r = p * 4 + wv;
        gs[p]  = s_gi[r];
        chs[p] = s_ch[r];
    }
    float2 go[8];
    #pragma unroll
    for (int p = 0; p < 8; ++p)
        go[p] = *(const float2*)&graph_out[gs[p] * NOISE + n0];

    #pragma unroll
    for (int p = 0; p < 8; ++p) {
        const int r = p * 4 + wv;
        const int row = row0 + r;
        float ax = bias.x + go[p].x + chs[p] * w1.x;
        float ay = bias.y + go[p].y + chs[p] * w1.y;
        const float4* __restrict__ tx4 = (const float4*)(s_tx + r * TXD);
        float4 t0 = tx4[0], t1 = tx4[1];
        ax = fmaf(t0.x, w3[0].x, ax); ay = fmaf(t0.x, w3[0].y, ay);
        ax = fmaf(t0.y, w3[1].x, ax); ay = fmaf(t0.y, w3[1].y, ay);
        ax = fmaf(t0.z, w3[2].x, ax); ay = fmaf(t0.z, w3[2].y, ay);
        ax = fmaf(t0.w, w3[3].x, ax); ay = fmaf(t0.w, w3[3].y, ay);
        ax = fmaf(t1.x, w3[4].x, ax); ay = fmaf(t1.x, w3[4].y, ay);
        ax = fmaf(t1.y, w3[5].x, ax); ay = fmaf(t1.y, w3[5].y, ay);
        ax = fmaf(t1.z, w3[6].x, ax); ay = fmaf(t1.z, w3[6].y, ay);
        ax = fmaf(t1.w, w3[7].x, ax); ay = fmaf(t1.w, w3[7].y, ay);
        const float* __restrict__ tg = s_trig + r * 36;
        #pragma unroll
        for (int q = 0; q < 8; ++q) {
            float4 t4 = *(const float4*)(tg + q * 4);   // broadcast b128
            ax = fmaf(t4.x, w2[4 * q + 0].x, ax); ay = fmaf(t4.x, w2[4 * q + 0].y, ay);
            ax = fmaf(t4.y, w2[4 * q + 1].x, ax); ay = fmaf(t4.y, w2[4 * q + 1].y, ay);
            ax = fmaf(t4.z, w2[4 * q + 2].x, ax); ay = fmaf(t4.z, w2[4 * q + 2].y, ay);
            ax = fmaf(t4.w, w2[4 * q + 3].x, ax); ay = fmaf(t4.w, w2[4 * q + 3].y, ay);
        }
        *(float2*)&out[(size_t)row * NOISE + n0] = make_float2(ax, ay);
    }
}

extern "C" void kernel_launch(void* const* d_in, const int* in_sizes, int n_in,
                              void* d_out, int out_size, void* d_ws, size_t ws_size,
                              hipStream_t stream) {
    const int*   bg      = (const int*)d_in[0];
    const float* chain   = (const float*)d_in[1];
    const float* trig_in = (const float*)d_in[2];
    const float* txs     = (const float*)d_in[3];
    const int*   edges   = (const int*)d_in[4];
    const float* gcn_w   = (const float*)d_in[5];
    const float* gcn_b   = (const float*)d_in[6];
    const float* trig_W  = (const float*)d_in[7];
    const float* trig_b  = (const float*)d_in[8];
    const float* emb_W   = (const float*)d_in[9];
    const float* emb_b   = (const float*)d_in[10];
    float* out = (float*)d_out;

    float* wsf       = (float*)d_ws;
    float* graph_out = wsf;                      // [64][128]
    int*   deg4      = (int*)(wsf + 8192);       // [64][4][2048]
    float* acc4      = wsf + 8192 + 524288;      // [64][4][2048]

    deg_kernel<<<NG * 4, 256, 0, stream>>>(edges, deg4, graph_out);
    acc_kernel<<<NG * 4, 256, 0, stream>>>(edges, deg4, acc4);
    fold_kernel<<<NG * 16, 256, 0, stream>>>(deg4, acc4, gcn_w, gcn_b, emb_W,
                                             graph_out);
    main_kernel<<<BB / ROWS, 256, 0, stream>>>(bg, chain, trig_in, txs, trig_W,
                                               trig_b, emb_W, emb_b, graph_out, out);
}